// Round 10
// baseline (372.004 us; speedup 1.0000x reference)
//
#include <hip/hip_runtime.h>
#include <hip/hip_bf16.h>

#define H 8
#define C 16
#define HC 128
#define NEG_SLOPE 0.2f

// ---------------- init: zero the 8-way degree counters ----------------
__global__ void init_kernel(int* __restrict__ deg8, int n) {
    int i = blockIdx.x * 256 + threadIdx.x;
    if (i < n) deg8[i] = 0;
}

// ---------------- 8-way histogram (4 edges/thread) + gptr boundaries ----------------
__global__ void hist8_gptr_kernel(const int* __restrict__ ei, const int* __restrict__ batch,
                                  int* __restrict__ deg8, int* __restrict__ gptr,
                                  int E, int N, int G) {
    int t = blockIdx.x * 256 + threadIdx.x;
    int* dg = deg8 + (size_t)(blockIdx.x & 7) * N;
    int e0 = t * 4;
    if (e0 + 3 < E) {
        int4 d4 = *(const int4*)(ei + E + e0);
        atomicAdd(&dg[d4.x], 1);
        atomicAdd(&dg[d4.y], 1);
        atomicAdd(&dg[d4.z], 1);
        atomicAdd(&dg[d4.w], 1);
    } else if (e0 < E) {
        for (int j = e0; j < E; ++j) atomicAdd(&dg[ei[E + j]], 1);
    }
    int n0 = t * 4;
    if (n0 < N) {
        int v0 = batch[n0];
        int v1 = (n0 + 1 < N) ? batch[n0 + 1] : v0;
        int v2 = (n0 + 2 < N) ? batch[n0 + 2] : v1;
        int v3 = (n0 + 3 < N) ? batch[n0 + 3] : v2;
        int vals[4] = {v0, v1, v2, v3};
        int prev = (n0 == 0) ? -1 : batch[n0 - 1];
        for (int j = 0; j < 4; ++j) {
            int i = n0 + j;
            if (i >= N) break;
            int cur = vals[j];
            if (cur != prev)
                for (int g = prev + 1; g <= cur; ++g) gptr[g] = i;
            if (i == N - 1)
                for (int g = cur + 1; g <= G; ++g) gptr[g] = N;
            prev = cur;
        }
    }
}

// ---------------- reduce 8 copies -> deg (incl. self loop) ----------------
__global__ void deg_reduce_kernel(const int* __restrict__ deg8, int* __restrict__ deg, int N) {
    int d = blockIdx.x * 256 + threadIdx.x;
    if (d >= N) return;
    int s = 1;  // self loop
#pragma unroll
    for (int c = 0; c < 8; ++c) s += deg8[(size_t)c * N + d];
    deg[d] = s;
}

// ======== 3-phase coalesced exclusive scan (pad16 applied to inputs) ========
__global__ void scan_blk_kernel(const int* __restrict__ a, int* __restrict__ o,
                                int* __restrict__ p, int n) {
    __shared__ int sh[256];
    int tid = threadIdx.x;
    int base = blockIdx.x * 1024 + tid * 4;
    int4 v = make_int4(0, 0, 0, 0);
    if (base + 3 < n) v = *(const int4*)(a + base);
    else {
        if (base < n)     v.x = a[base];
        if (base + 1 < n) v.y = a[base + 1];
        if (base + 2 < n) v.z = a[base + 2];
        if (base + 3 < n) v.w = a[base + 3];
    }
    v.x = (v.x + 15) & ~15; v.y = (v.y + 15) & ~15;
    v.z = (v.z + 15) & ~15; v.w = (v.w + 15) & ~15;
    if (base >= n)     v.x = 0;
    if (base + 1 >= n) v.y = 0;
    if (base + 2 >= n) v.z = 0;
    if (base + 3 >= n) v.w = 0;
    int s = v.x + v.y + v.z + v.w;
    sh[tid] = s;
    __syncthreads();
    for (int off = 1; off < 256; off <<= 1) {
        int t = (tid >= off) ? sh[tid - off] : 0;
        __syncthreads();
        sh[tid] += t;
        __syncthreads();
    }
    int excl = sh[tid] - s;
    int4 ov;
    ov.x = excl; ov.y = ov.x + v.x; ov.z = ov.y + v.y; ov.w = ov.z + v.z;
    if (base + 3 < n) *(int4*)(o + base) = ov;
    else {
        if (base < n)     o[base] = ov.x;
        if (base + 1 < n) o[base + 1] = ov.y;
        if (base + 2 < n) o[base + 2] = ov.z;
        if (base + 3 < n) o[base + 3] = ov.w;
    }
    if (tid == 255) p[blockIdx.x] = sh[255];
}

__global__ void scan_part_kernel(int* __restrict__ p, int* __restrict__ tot, int nb) {
    __shared__ int sh[256];
    int tid = threadIdx.x;
    int v = (tid < nb) ? p[tid] : 0;
    sh[tid] = v;
    __syncthreads();
    for (int off = 1; off < 256; off <<= 1) {
        int t = (tid >= off) ? sh[tid - off] : 0;
        __syncthreads();
        sh[tid] += t;
        __syncthreads();
    }
    if (tid < nb) p[tid] = sh[tid] - v;
    if (tid == 255) *tot = sh[255];
}

__global__ void scan_add_kernel(int* __restrict__ o, const int* __restrict__ p, int n) {
    int off = p[blockIdx.x];
    int base = blockIdx.x * 1024 + threadIdx.x * 4;
    if (base + 3 < n) {
        int4 v = *(const int4*)(o + base);
        v.x += off; v.y += off; v.z += off; v.w += off;
        *(int4*)(o + base) = v;
    } else {
        if (base < n)     o[base] += off;
        if (base + 1 < n) o[base + 1] += off;
        if (base + 2 < n) o[base + 2] += off;
        if (base + 3 < n) o[base + 3] += off;
    }
}

// ---------------- per-copy cursor bases + self-loop + sentinel pads ----------------
__global__ void base_fill_kernel(int* __restrict__ deg8 /* in: counts, out: cursors */,
                                 const int* __restrict__ rowptr, int* __restrict__ csr, int N) {
    int d = blockIdx.x * 256 + threadIdx.x;
    if (d >= N) return;
    int base = rowptr[d];
    csr[base] = d;  // self loop at slot 0
    int run = base + 1;
    int cnt[8];
#pragma unroll
    for (int c = 0; c < 8; ++c) cnt[c] = deg8[(size_t)c * N + d];
#pragma unroll
    for (int c = 0; c < 8; ++c) { deg8[(size_t)c * N + d] = run; run += cnt[c]; }
    int rend = rowptr[d + 1];
    for (int p = run; p < rend; ++p) csr[p] = N;  // sentinel pads
    if (d == 0) {
        int tot = rowptr[N];
        for (int k = 0; k < 64; ++k) csr[tot + k] = N;  // prefetch margin
    }
}

// ---------------- 8-way scatter (4 edges/thread), copy mapping == hist8 ----------------
__global__ void scatter8_kernel(const int* __restrict__ ei, int* __restrict__ base8,
                                int* __restrict__ csr, int E, int N) {
    int t = blockIdx.x * 256 + threadIdx.x;
    int* cur = base8 + (size_t)(blockIdx.x & 7) * N;
    int e0 = t * 4;
    if (e0 + 3 < E) {
        int4 s4 = *(const int4*)(ei + e0);
        int4 d4 = *(const int4*)(ei + E + e0);
        int p;
        p = atomicAdd(&cur[d4.x], 1); csr[p] = s4.x;
        p = atomicAdd(&cur[d4.y], 1); csr[p] = s4.y;
        p = atomicAdd(&cur[d4.z], 1); csr[p] = s4.z;
        p = atomicAdd(&cur[d4.w], 1); csr[p] = s4.w;
    } else if (e0 < E) {
        for (int j = e0; j < E; ++j) {
            int p = atomicAdd(&cur[ei[E + j]], 1);
            csr[p] = ei[j];
        }
    }
}

// ---------------- fused GEMM + attention coefficients ----------------
// 64x128 tile, 256 threads, each thread 8 rows x 4 cols; W double-buffered.
// Block 0 additionally writes the sentinel row (h[n]=0, asrc[n]=-inf).
template <int K>
__global__ void gemm_att_kernel(const float* __restrict__ x, const float* __restrict__ W,
                                const float* __restrict__ as_, const float* __restrict__ ad_,
                                float* __restrict__ h, float* __restrict__ asrc,
                                float* __restrict__ adst, int n) {
    const int ROWS = 64;
    __shared__ float xs[ROWS][HC];
    int tx = threadIdx.x & 31;
    int ty = threadIdx.x >> 5;
    int row0 = blockIdx.x * ROWS;

    if (blockIdx.x == 0) {
        if (threadIdx.x < HC) h[(size_t)n * HC + threadIdx.x] = 0.f;
        if (threadIdx.x < H)  asrc[(size_t)n * H + threadIdx.x] = -INFINITY;
    }

    const int NV = ROWS * K / 4;
    for (int idx = threadIdx.x; idx < NV; idx += 256) {
        int rr = idx / (K / 4), kk = idx % (K / 4);
        int gr = row0 + rr;
        float4 v = (gr < n) ? ((const float4*)(x + (size_t)gr * K))[kk]
                            : make_float4(0.f, 0.f, 0.f, 0.f);
        *(float4*)(&xs[rr][kk * 4]) = v;
    }
    __syncthreads();

    const float* Wc = W + tx * 4;
    float acc[8][4];
#pragma unroll
    for (int r = 0; r < 8; ++r)
#pragma unroll
        for (int c = 0; c < 4; ++c) acc[r][c] = 0.f;

    float4 wv[4], wn[4];
#pragma unroll
    for (int kk = 0; kk < 4; ++kk)
        wv[kk] = *(const float4*)(Wc + (size_t)kk * HC);

    for (int k = 0; k < K; k += 4) {
        if (k + 4 < K) {
#pragma unroll
            for (int kk = 0; kk < 4; ++kk)
                wn[kk] = *(const float4*)(Wc + (size_t)(k + 4 + kk) * HC);
        }
#pragma unroll
        for (int r = 0; r < 8; ++r) {
            float4 xr = *(const float4*)(&xs[ty * 8 + r][k]);
            acc[r][0] = fmaf(xr.x, wv[0].x, acc[r][0]);
            acc[r][1] = fmaf(xr.x, wv[0].y, acc[r][1]);
            acc[r][2] = fmaf(xr.x, wv[0].z, acc[r][2]);
            acc[r][3] = fmaf(xr.x, wv[0].w, acc[r][3]);
            acc[r][0] = fmaf(xr.y, wv[1].x, acc[r][0]);
            acc[r][1] = fmaf(xr.y, wv[1].y, acc[r][1]);
            acc[r][2] = fmaf(xr.y, wv[1].z, acc[r][2]);
            acc[r][3] = fmaf(xr.y, wv[1].w, acc[r][3]);
            acc[r][0] = fmaf(xr.z, wv[2].x, acc[r][0]);
            acc[r][1] = fmaf(xr.z, wv[2].y, acc[r][1]);
            acc[r][2] = fmaf(xr.z, wv[2].z, acc[r][2]);
            acc[r][3] = fmaf(xr.z, wv[2].w, acc[r][3]);
            acc[r][0] = fmaf(xr.w, wv[3].x, acc[r][0]);
            acc[r][1] = fmaf(xr.w, wv[3].y, acc[r][1]);
            acc[r][2] = fmaf(xr.w, wv[3].z, acc[r][2]);
            acc[r][3] = fmaf(xr.w, wv[3].w, acc[r][3]);
        }
#pragma unroll
        for (int kk = 0; kk < 4; ++kk) wv[kk] = wn[kk];
    }
    __syncthreads();
#pragma unroll
    for (int r = 0; r < 8; ++r) {
        float4 o = make_float4(acc[r][0], acc[r][1], acc[r][2], acc[r][3]);
        *(float4*)(&xs[ty * 8 + r][tx * 4]) = o;
        int row = row0 + ty * 8 + r;
        if (row < n) *(float4*)(h + (size_t)row * HC + tx * 4) = o;
    }
    __syncthreads();

#pragma unroll
    for (int rep = 0; rep < 2; ++rep) {
        int pidx = threadIdx.x + rep * 256;
        int row = pidx >> 3;
        int hd = pidx & 7;
        if (row0 + row < n) {
            const float4* hv = (const float4*)&xs[row][hd * 16];
            const float4* sv = (const float4*)(as_ + hd * 16);
            const float4* dv = (const float4*)(ad_ + hd * 16);
            float s = 0.f, d = 0.f;
#pragma unroll
            for (int j = 0; j < 4; ++j) {
                float4 a = hv[j], u = sv[j], v = dv[j];
                s += a.x * u.x + a.y * u.y + a.z * u.z + a.w * u.w;
                d += a.x * v.x + a.y * v.y + a.z * v.z + a.w * v.w;
            }
            asrc[(size_t)(row0 + row) * H + hd] = s;
            adst[(size_t)(row0 + row) * H + hd] = d;
        }
    }
}

// ---------------- fused GAT aggregation: one wave per destination ----------------
// No-max softmax; rows padded to multiple of 16 with sentinel src=N (w=0).
// 16-wide groups: typical row (deg<=15) has ALL value gathers issued in the
// prologue; loop iterations are fully straight-line.
__global__ void gat_agg_kernel(const int* __restrict__ rowptr, const int* __restrict__ csr_src,
                               const float* __restrict__ h, const float* __restrict__ asrc,
                               const float* __restrict__ adst, const float* __restrict__ bias,
                               float* __restrict__ out, int N) {
    int dst = (blockIdx.x * 256 + threadIdx.x) >> 6;  // one wave per dst
    if (dst >= N) return;
    int lane = threadIdx.x & 63;
    int hd = lane >> 3;
    int beg = rowptr[dst], end = rowptr[dst + 1];
    float ad = adst[(size_t)dst * H + hd];
    const float2* h2 = (const float2*)h;  // row stride = 64 float2

    float z = 0.f, a0 = 0.f, a1 = 0.f;
    int i0, i1, i2, i3, i4, i5, i6, i7, i8, i9, i10, i11, i12, i13, i14, i15;
    float e0, e1, e2, e3, e4, e5, e6, e7, e8, e9, e10, e11, e12, e13, e14, e15;
    float2 v0, v1, v2, v3, v4, v5, v6, v7, v8, v9, v10, v11, v12, v13, v14, v15;

#define LOADI(S, J) i##S = csr_src[(J)];
#define LOADV(S)                                                           \
    { e##S = asrc[(size_t)i##S * H + hd]; v##S = h2[(size_t)i##S * 64 + lane]; }
#define PROCE(S)                                                           \
    {   float e = e##S + ad;                                               \
        e = e > 0.f ? e : NEG_SLOPE * e;                                   \
        float w = __expf(e);                                               \
        z += w;                                                            \
        a0 = fmaf(w, v##S.x, a0);                                          \
        a1 = fmaf(w, v##S.y, a1);                                          \
    }
#define LOADI_G(B)                                                          \
    LOADI(0,(B))      LOADI(1,(B)+1)   LOADI(2,(B)+2)   LOADI(3,(B)+3)     \
    LOADI(4,(B)+4)    LOADI(5,(B)+5)   LOADI(6,(B)+6)   LOADI(7,(B)+7)     \
    LOADI(8,(B)+8)    LOADI(9,(B)+9)   LOADI(10,(B)+10) LOADI(11,(B)+11)   \
    LOADI(12,(B)+12)  LOADI(13,(B)+13) LOADI(14,(B)+14) LOADI(15,(B)+15)
#define LOADV_G                                                             \
    LOADV(0)  LOADV(1)  LOADV(2)  LOADV(3)  LOADV(4)  LOADV(5)  LOADV(6)  LOADV(7) \
    LOADV(8)  LOADV(9)  LOADV(10) LOADV(11) LOADV(12) LOADV(13) LOADV(14) LOADV(15)

    // prologue: idx g0, vals g0, idx g1
    LOADI_G(beg)
    LOADV_G
    LOADI_G(beg + 16)

    for (int j = beg; j < end; j += 16) {
        PROCE(0)  LOADV(0)
        PROCE(1)  LOADV(1)
        PROCE(2)  LOADV(2)
        PROCE(3)  LOADV(3)
        PROCE(4)  LOADV(4)
        PROCE(5)  LOADV(5)
        PROCE(6)  LOADV(6)
        PROCE(7)  LOADV(7)
        PROCE(8)  LOADV(8)
        PROCE(9)  LOADV(9)
        PROCE(10) LOADV(10)
        PROCE(11) LOADV(11)
        PROCE(12) LOADV(12)
        PROCE(13) LOADV(13)
        PROCE(14) LOADV(14)
        PROCE(15) LOADV(15)
        LOADI_G(j + 32)
    }
#undef LOADI
#undef LOADV
#undef PROCE
#undef LOADI_G
#undef LOADV_G
    float inv = 1.f / (z + 1e-16f);
    int c2 = lane * 2;
    float r0 = fmaxf(a0 * inv + bias[c2], 0.f);
    float r1 = fmaxf(a1 * inv + bias[c2 + 1], 0.f);
    *(float2*)(out + (size_t)dst * HC + c2) = make_float2(r0, r1);
}

// ---------------- fused global mean pool + MLP: one block (128 threads) per graph ---
__global__ void pool_mlp_kernel(const float* __restrict__ x, const int* __restrict__ gptr,
                                const float* __restrict__ fc1w, const float* __restrict__ fc1b,
                                const float* __restrict__ fc2w, const float* __restrict__ fc2b,
                                float* __restrict__ out, int G) {
    __shared__ float sp[HC];
    __shared__ float sh[10];
    int g = blockIdx.x;
    int c = threadIdx.x;  // 0..127
    int beg = gptr[g], end = gptr[g + 1];
    float acc = 0.f;
    for (int n = beg; n < end; ++n) acc += x[(size_t)n * HC + c];
    sp[c] = acc / fmaxf((float)(end - beg), 1.f);
    __syncthreads();
    if (c < 10) {
        float s = fc1b[c];
        for (int k = 0; k < HC; ++k) s = fmaf(sp[k], fc1w[k * 10 + c], s);
        sh[c] = fmaxf(s, 0.f);
    }
    __syncthreads();
    if (c == 0) {
        float o = fc2b[0];
#pragma unroll
        for (int j = 0; j < 10; ++j) o = fmaf(sh[j], fc2w[j], o);
        out[g] = o;
    }
}

extern "C" void kernel_launch(void* const* d_in, const int* in_sizes, int n_in,
                              void* d_out, int out_size, void* d_ws, size_t ws_size,
                              hipStream_t stream) {
    const int N = in_sizes[0] / 64;   // 50000
    const int E = in_sizes[1] / 2;    // 600000
    const int G = out_size;           // 500
    const int CSR_CAP = E + 16 * N + 64;  // pad16 worst case + prefetch margin

    const float* x     = (const float*)d_in[0];
    const int*   ei    = (const int*)d_in[1];
    const int*   batch = (const int*)d_in[2];
    const float* W1 = (const float*)d_in[3];
    const float* as1 = (const float*)d_in[4];
    const float* ad1 = (const float*)d_in[5];
    const float* b1 = (const float*)d_in[6];
    const float* W2 = (const float*)d_in[7];
    const float* as2 = (const float*)d_in[8];
    const float* ad2 = (const float*)d_in[9];
    const float* b2 = (const float*)d_in[10];
    const float* W3 = (const float*)d_in[11];
    const float* as3 = (const float*)d_in[12];
    const float* ad3 = (const float*)d_in[13];
    const float* b3 = (const float*)d_in[14];
    const float* fc1w = (const float*)d_in[15];
    const float* fc1b = (const float*)d_in[16];
    const float* fc2w = (const float*)d_in[17];
    const float* fc2b = (const float*)d_in[18];

    // -------- workspace layout --------
    float* ws = (float*)d_ws;
    float* h    = ws;                            // (N+1)*128
    float* xb0  = h + (size_t)(N + 1) * HC;      // N*128
    float* xb1  = xb0 + (size_t)N * HC;          // N*128
    float* asrc = xb1 + (size_t)N * HC;          // (N+1)*8
    float* adst = asrc + (size_t)(N + 1) * H;    // N*8
    int* ints   = (int*)(adst + (size_t)N * H);
    int* deg8   = ints;                          // 8*N  (becomes base8 cursors)
    int* deg    = deg8 + (size_t)8 * N;          // N
    int* rowptr = deg + N;                       // N+16
    int* gptr   = rowptr + N + 16;               // G+16
    int* partN  = gptr + G + 16;                 // 256
    int* csr    = partN + 256;                   // CSR_CAP

    dim3 blk(256);
    int grid4   = ((E + 3) / 4 + 255) / 256;     // covers E/4 and N/4 threads
    int grid_n  = (N + 255) / 256;
    int grid_agg = (N * 64 + 255) / 256;
    int nbN = (N + 1023) / 1024;

    // -------- one-time CSR build (graph shared by all 3 layers) --------
    init_kernel<<<(8 * N + 255) / 256, blk, 0, stream>>>(deg8, 8 * N);
    hist8_gptr_kernel<<<grid4, blk, 0, stream>>>(ei, batch, deg8, gptr, E, N, G);
    deg_reduce_kernel<<<grid_n, blk, 0, stream>>>(deg8, deg, N);
    scan_blk_kernel<<<nbN, blk, 0, stream>>>(deg, rowptr, partN, N);
    scan_part_kernel<<<1, blk, 0, stream>>>(partN, rowptr + N, nbN);
    scan_add_kernel<<<nbN, blk, 0, stream>>>(rowptr, partN, N);
    base_fill_kernel<<<grid_n, blk, 0, stream>>>(deg8, rowptr, csr, N);
    scatter8_kernel<<<grid4, blk, 0, stream>>>(ei, deg8, csr, E, N);

    auto run_layer = [&](const float* xin, int K, const float* W, const float* as_,
                         const float* ad_, const float* b, float* out) {
        if (K == 64)
            gemm_att_kernel<64><<<(N + 63) / 64, blk, 0, stream>>>(xin, W, as_, ad_,
                                                                   h, asrc, adst, N);
        else
            gemm_att_kernel<128><<<(N + 63) / 64, blk, 0, stream>>>(xin, W, as_, ad_,
                                                                    h, asrc, adst, N);
        gat_agg_kernel<<<grid_agg, blk, 0, stream>>>(rowptr, csr, h, asrc, adst, b, out, N);
    };

    run_layer(x,   64,  W1, as1, ad1, b1, xb0);
    run_layer(xb0, 128, W2, as2, ad2, b2, xb1);
    run_layer(xb1, 128, W3, as3, ad3, b3, xb0);

    pool_mlp_kernel<<<G, dim3(128), 0, stream>>>(xb0, gptr, fc1w, fc1b, fc2w, fc2b,
                                                 (float*)d_out, G);
}

// Round 11
// 371.212 us; speedup vs baseline: 1.0021x; 1.0021x over previous
//
#include <hip/hip_runtime.h>
#include <hip/hip_bf16.h>

#define H 8
#define C 16
#define HC 128
#define NEG_SLOPE 0.2f

// ---------------- init: zero the 8-way degree counters ----------------
__global__ void init_kernel(int* __restrict__ deg8, int n) {
    int i = blockIdx.x * 256 + threadIdx.x;
    if (i < n) deg8[i] = 0;
}

// ---------------- 8-way histogram (8 edges/thread) + gptr boundaries ----------------
__global__ void hist8_gptr_kernel(const int* __restrict__ ei, const int* __restrict__ batch,
                                  int* __restrict__ deg8, int* __restrict__ gptr,
                                  int E, int N, int G) {
    int t = blockIdx.x * 256 + threadIdx.x;
    int* dg = deg8 + (size_t)(blockIdx.x & 7) * N;
    int e0 = t * 8;
    if (e0 + 7 < E) {
        int4 d4a = *(const int4*)(ei + E + e0);
        int4 d4b = *(const int4*)(ei + E + e0 + 4);
        atomicAdd(&dg[d4a.x], 1);
        atomicAdd(&dg[d4a.y], 1);
        atomicAdd(&dg[d4a.z], 1);
        atomicAdd(&dg[d4a.w], 1);
        atomicAdd(&dg[d4b.x], 1);
        atomicAdd(&dg[d4b.y], 1);
        atomicAdd(&dg[d4b.z], 1);
        atomicAdd(&dg[d4b.w], 1);
    } else if (e0 < E) {
        for (int j = e0; j < E; ++j) atomicAdd(&dg[ei[E + j]], 1);
    }
    int n0 = t * 8;
    if (n0 < N) {
        int prev = (n0 == 0) ? -1 : batch[n0 - 1];
        for (int j = 0; j < 8 && n0 + j < N; ++j) {
            int i = n0 + j;
            int cur = batch[i];
            if (cur != prev)
                for (int g = prev + 1; g <= cur; ++g) gptr[g] = i;
            if (i == N - 1)
                for (int g = cur + 1; g <= G; ++g) gptr[g] = N;
            prev = cur;
        }
    }
}

// ---------------- reduce 8 copies -> deg (incl. self loop) ----------------
__global__ void deg_reduce_kernel(const int* __restrict__ deg8, int* __restrict__ deg, int N) {
    int d = blockIdx.x * 256 + threadIdx.x;
    if (d >= N) return;
    int s = 1;  // self loop
#pragma unroll
    for (int c = 0; c < 8; ++c) s += deg8[(size_t)c * N + d];
    deg[d] = s;
}

// ======== 3-phase coalesced exclusive scan (pad8 applied to inputs) ========
__global__ void scan_blk_kernel(const int* __restrict__ a, int* __restrict__ o,
                                int* __restrict__ p, int n) {
    __shared__ int sh[256];
    int tid = threadIdx.x;
    int base = blockIdx.x * 1024 + tid * 4;
    int4 v = make_int4(0, 0, 0, 0);
    if (base + 3 < n) v = *(const int4*)(a + base);
    else {
        if (base < n)     v.x = a[base];
        if (base + 1 < n) v.y = a[base + 1];
        if (base + 2 < n) v.z = a[base + 2];
        if (base + 3 < n) v.w = a[base + 3];
    }
    v.x = (v.x + 7) & ~7; v.y = (v.y + 7) & ~7;
    v.z = (v.z + 7) & ~7; v.w = (v.w + 7) & ~7;
    if (base >= n)     v.x = 0;
    if (base + 1 >= n) v.y = 0;
    if (base + 2 >= n) v.z = 0;
    if (base + 3 >= n) v.w = 0;
    int s = v.x + v.y + v.z + v.w;
    sh[tid] = s;
    __syncthreads();
    for (int off = 1; off < 256; off <<= 1) {
        int t = (tid >= off) ? sh[tid - off] : 0;
        __syncthreads();
        sh[tid] += t;
        __syncthreads();
    }
    int excl = sh[tid] - s;
    int4 ov;
    ov.x = excl; ov.y = ov.x + v.x; ov.z = ov.y + v.y; ov.w = ov.z + v.z;
    if (base + 3 < n) *(int4*)(o + base) = ov;
    else {
        if (base < n)     o[base] = ov.x;
        if (base + 1 < n) o[base + 1] = ov.y;
        if (base + 2 < n) o[base + 2] = ov.z;
        if (base + 3 < n) o[base + 3] = ov.w;
    }
    if (tid == 255) p[blockIdx.x] = sh[255];
}

__global__ void scan_part_kernel(int* __restrict__ p, int* __restrict__ tot, int nb) {
    __shared__ int sh[256];
    int tid = threadIdx.x;
    int v = (tid < nb) ? p[tid] : 0;
    sh[tid] = v;
    __syncthreads();
    for (int off = 1; off < 256; off <<= 1) {
        int t = (tid >= off) ? sh[tid - off] : 0;
        __syncthreads();
        sh[tid] += t;
        __syncthreads();
    }
    if (tid < nb) p[tid] = sh[tid] - v;
    if (tid == 255) *tot = sh[255];
}

__global__ void scan_add_kernel(int* __restrict__ o, const int* __restrict__ p, int n) {
    int off = p[blockIdx.x];
    int base = blockIdx.x * 1024 + threadIdx.x * 4;
    if (base + 3 < n) {
        int4 v = *(const int4*)(o + base);
        v.x += off; v.y += off; v.z += off; v.w += off;
        *(int4*)(o + base) = v;
    } else {
        if (base < n)     o[base] += off;
        if (base + 1 < n) o[base + 1] += off;
        if (base + 2 < n) o[base + 2] += off;
        if (base + 3 < n) o[base + 3] += off;
    }
}

// ---------------- per-copy cursor bases + self-loop + sentinel pads ----------------
__global__ void base_fill_kernel(int* __restrict__ deg8 /* in: counts, out: cursors */,
                                 const int* __restrict__ rowptr, int* __restrict__ csr, int N) {
    int d = blockIdx.x * 256 + threadIdx.x;
    if (d >= N) return;
    int base = rowptr[d];
    csr[base] = d;  // self loop at slot 0
    int run = base + 1;
    int cnt[8];
#pragma unroll
    for (int c = 0; c < 8; ++c) cnt[c] = deg8[(size_t)c * N + d];
#pragma unroll
    for (int c = 0; c < 8; ++c) { deg8[(size_t)c * N + d] = run; run += cnt[c]; }
    int rend = rowptr[d + 1];
    for (int p = run; p < rend; ++p) csr[p] = N;  // sentinel pads
    if (d == 0) {
        int tot = rowptr[N];
        for (int k = 0; k < 64; ++k) csr[tot + k] = N;  // prefetch margin
    }
}

// ---------------- 8-way scatter (8 edges/thread), copy mapping == hist8 ----------------
__global__ void scatter8_kernel(const int* __restrict__ ei, int* __restrict__ base8,
                                int* __restrict__ csr, int E, int N) {
    int t = blockIdx.x * 256 + threadIdx.x;
    int* cur = base8 + (size_t)(blockIdx.x & 7) * N;
    int e0 = t * 8;
    if (e0 + 7 < E) {
        int4 s4a = *(const int4*)(ei + e0);
        int4 s4b = *(const int4*)(ei + e0 + 4);
        int4 d4a = *(const int4*)(ei + E + e0);
        int4 d4b = *(const int4*)(ei + E + e0 + 4);
        int p;
        p = atomicAdd(&cur[d4a.x], 1); csr[p] = s4a.x;
        p = atomicAdd(&cur[d4a.y], 1); csr[p] = s4a.y;
        p = atomicAdd(&cur[d4a.z], 1); csr[p] = s4a.z;
        p = atomicAdd(&cur[d4a.w], 1); csr[p] = s4a.w;
        p = atomicAdd(&cur[d4b.x], 1); csr[p] = s4b.x;
        p = atomicAdd(&cur[d4b.y], 1); csr[p] = s4b.y;
        p = atomicAdd(&cur[d4b.z], 1); csr[p] = s4b.z;
        p = atomicAdd(&cur[d4b.w], 1); csr[p] = s4b.w;
    } else if (e0 < E) {
        for (int j = e0; j < E; ++j) {
            int p = atomicAdd(&cur[ei[E + j]], 1);
            csr[p] = ei[j];
        }
    }
}

// ---------------- fused GEMM + attention coefficients ----------------
// 64x128 tile, 256 threads, each thread 8 rows x 4 cols; W double-buffered.
// Block 0 additionally writes the sentinel row (h[n]=0, asrc[n]=-inf).
template <int K>
__global__ void gemm_att_kernel(const float* __restrict__ x, const float* __restrict__ W,
                                const float* __restrict__ as_, const float* __restrict__ ad_,
                                float* __restrict__ h, float* __restrict__ asrc,
                                float* __restrict__ adst, int n) {
    const int ROWS = 64;
    __shared__ float xs[ROWS][HC];
    int tx = threadIdx.x & 31;
    int ty = threadIdx.x >> 5;
    int row0 = blockIdx.x * ROWS;

    if (blockIdx.x == 0) {
        if (threadIdx.x < HC) h[(size_t)n * HC + threadIdx.x] = 0.f;
        if (threadIdx.x < H)  asrc[(size_t)n * H + threadIdx.x] = -INFINITY;
    }

    const int NV = ROWS * K / 4;
    for (int idx = threadIdx.x; idx < NV; idx += 256) {
        int rr = idx / (K / 4), kk = idx % (K / 4);
        int gr = row0 + rr;
        float4 v = (gr < n) ? ((const float4*)(x + (size_t)gr * K))[kk]
                            : make_float4(0.f, 0.f, 0.f, 0.f);
        *(float4*)(&xs[rr][kk * 4]) = v;
    }
    __syncthreads();

    const float* Wc = W + tx * 4;
    float acc[8][4];
#pragma unroll
    for (int r = 0; r < 8; ++r)
#pragma unroll
        for (int c = 0; c < 4; ++c) acc[r][c] = 0.f;

    float4 wv[4], wn[4];
#pragma unroll
    for (int kk = 0; kk < 4; ++kk)
        wv[kk] = *(const float4*)(Wc + (size_t)kk * HC);

    for (int k = 0; k < K; k += 4) {
        if (k + 4 < K) {
#pragma unroll
            for (int kk = 0; kk < 4; ++kk)
                wn[kk] = *(const float4*)(Wc + (size_t)(k + 4 + kk) * HC);
        }
#pragma unroll
        for (int r = 0; r < 8; ++r) {
            float4 xr = *(const float4*)(&xs[ty * 8 + r][k]);
            acc[r][0] = fmaf(xr.x, wv[0].x, acc[r][0]);
            acc[r][1] = fmaf(xr.x, wv[0].y, acc[r][1]);
            acc[r][2] = fmaf(xr.x, wv[0].z, acc[r][2]);
            acc[r][3] = fmaf(xr.x, wv[0].w, acc[r][3]);
            acc[r][0] = fmaf(xr.y, wv[1].x, acc[r][0]);
            acc[r][1] = fmaf(xr.y, wv[1].y, acc[r][1]);
            acc[r][2] = fmaf(xr.y, wv[1].z, acc[r][2]);
            acc[r][3] = fmaf(xr.y, wv[1].w, acc[r][3]);
            acc[r][0] = fmaf(xr.z, wv[2].x, acc[r][0]);
            acc[r][1] = fmaf(xr.z, wv[2].y, acc[r][1]);
            acc[r][2] = fmaf(xr.z, wv[2].z, acc[r][2]);
            acc[r][3] = fmaf(xr.z, wv[2].w, acc[r][3]);
            acc[r][0] = fmaf(xr.w, wv[3].x, acc[r][0]);
            acc[r][1] = fmaf(xr.w, wv[3].y, acc[r][1]);
            acc[r][2] = fmaf(xr.w, wv[3].z, acc[r][2]);
            acc[r][3] = fmaf(xr.w, wv[3].w, acc[r][3]);
        }
#pragma unroll
        for (int kk = 0; kk < 4; ++kk) wv[kk] = wn[kk];
    }
    __syncthreads();
#pragma unroll
    for (int r = 0; r < 8; ++r) {
        float4 o = make_float4(acc[r][0], acc[r][1], acc[r][2], acc[r][3]);
        *(float4*)(&xs[ty * 8 + r][tx * 4]) = o;
        int row = row0 + ty * 8 + r;
        if (row < n) *(float4*)(h + (size_t)row * HC + tx * 4) = o;
    }
    __syncthreads();

#pragma unroll
    for (int rep = 0; rep < 2; ++rep) {
        int pidx = threadIdx.x + rep * 256;
        int row = pidx >> 3;
        int hd = pidx & 7;
        if (row0 + row < n) {
            const float4* hv = (const float4*)&xs[row][hd * 16];
            const float4* sv = (const float4*)(as_ + hd * 16);
            const float4* dv = (const float4*)(ad_ + hd * 16);
            float s = 0.f, d = 0.f;
#pragma unroll
            for (int j = 0; j < 4; ++j) {
                float4 a = hv[j], u = sv[j], v = dv[j];
                s += a.x * u.x + a.y * u.y + a.z * u.z + a.w * u.w;
                d += a.x * v.x + a.y * v.y + a.z * v.z + a.w * v.w;
            }
            asrc[(size_t)(row0 + row) * H + hd] = s;
            adst[(size_t)(row0 + row) * H + hd] = d;
        }
    }
}

// ---------------- fused GAT aggregation: TWO waves per destination ----------------
// No-max softmax; pad8 sentinel rows. Each wave handles half the row (8-aligned
// split) with the 8-deep 3-stage pipeline; partials (z,a0,a1) combined in LDS.
__global__ __launch_bounds__(256, 8)
void gat_agg_kernel(const int* __restrict__ rowptr, const int* __restrict__ csr_src,
                    const float* __restrict__ h, const float* __restrict__ asrc,
                    const float* __restrict__ adst, const float* __restrict__ bias,
                    float* __restrict__ out, int N) {
    __shared__ float red[4][3][64];
    int wid = threadIdx.x >> 6;            // 0..3
    int half = wid & 1;
    int dst = blockIdx.x * 2 + (wid >> 1); // 2 dsts per block
    int lane = threadIdx.x & 63;
    int hd = lane >> 3;

    float z = 0.f, a0 = 0.f, a1 = 0.f;
    if (dst < N) {
        int beg = rowptr[dst], end = rowptr[dst + 1];
        int len = end - beg;                      // multiple of 8
        int hl = ((len >> 1) + 7) & ~7;           // 8-aligned half
        int b0 = half ? beg + hl : beg;
        int e0r = half ? end : beg + hl;
        if (b0 < e0r) {
            float ad = adst[(size_t)dst * H + hd];
            const float2* h2 = (const float2*)h;  // row stride = 64 float2
            int i0, i1, i2, i3, i4, i5, i6, i7;
            float e0, e1, e2, e3, e4, e5, e6, e7;
            float2 v0, v1, v2, v3, v4, v5, v6, v7;
#define LOADI(S, J) i##S = csr_src[(J)];
#define LOADV(S)                                                           \
    { e##S = asrc[(size_t)i##S * H + hd]; v##S = h2[(size_t)i##S * 64 + lane]; }
#define PROCE(S)                                                           \
    {   float e = e##S + ad;                                               \
        e = e > 0.f ? e : NEG_SLOPE * e;                                   \
        float w = __expf(e);                                               \
        z += w;                                                            \
        a0 = fmaf(w, v##S.x, a0);                                          \
        a1 = fmaf(w, v##S.y, a1);                                          \
    }
            LOADI(0, b0)     LOADI(1, b0 + 1) LOADI(2, b0 + 2) LOADI(3, b0 + 3)
            LOADI(4, b0 + 4) LOADI(5, b0 + 5) LOADI(6, b0 + 6) LOADI(7, b0 + 7)
            LOADV(0) LOADV(1) LOADV(2) LOADV(3) LOADV(4) LOADV(5) LOADV(6) LOADV(7)
            LOADI(0, b0 + 8)  LOADI(1, b0 + 9)  LOADI(2, b0 + 10) LOADI(3, b0 + 11)
            LOADI(4, b0 + 12) LOADI(5, b0 + 13) LOADI(6, b0 + 14) LOADI(7, b0 + 15)
            for (int j = b0; j < e0r; j += 8) {
                PROCE(0) LOADV(0)
                PROCE(1) LOADV(1)
                PROCE(2) LOADV(2)
                PROCE(3) LOADV(3)
                PROCE(4) LOADV(4)
                PROCE(5) LOADV(5)
                PROCE(6) LOADV(6)
                PROCE(7) LOADV(7)
                LOADI(0, j + 16) LOADI(1, j + 17) LOADI(2, j + 18) LOADI(3, j + 19)
                LOADI(4, j + 20) LOADI(5, j + 21) LOADI(6, j + 22) LOADI(7, j + 23)
            }
#undef LOADI
#undef LOADV
#undef PROCE
        }
    }
    red[wid][0][lane] = z;
    red[wid][1][lane] = a0;
    red[wid][2][lane] = a1;
    __syncthreads();
    if (half == 0 && dst < N) {
        z  += red[wid + 1][0][lane];
        a0 += red[wid + 1][1][lane];
        a1 += red[wid + 1][2][lane];
        float inv = 1.f / (z + 1e-16f);
        int c2 = lane * 2;
        float r0 = fmaxf(a0 * inv + bias[c2], 0.f);
        float r1 = fmaxf(a1 * inv + bias[c2 + 1], 0.f);
        *(float2*)(out + (size_t)dst * HC + c2) = make_float2(r0, r1);
    }
}

// ---------------- fused global mean pool + MLP: one block (128 threads) per graph ---
__global__ void pool_mlp_kernel(const float* __restrict__ x, const int* __restrict__ gptr,
                                const float* __restrict__ fc1w, const float* __restrict__ fc1b,
                                const float* __restrict__ fc2w, const float* __restrict__ fc2b,
                                float* __restrict__ out, int G) {
    __shared__ float sp[HC];
    __shared__ float sh[10];
    int g = blockIdx.x;
    int c = threadIdx.x;  // 0..127
    int beg = gptr[g], end = gptr[g + 1];
    float acc = 0.f;
    for (int n = beg; n < end; ++n) acc += x[(size_t)n * HC + c];
    sp[c] = acc / fmaxf((float)(end - beg), 1.f);
    __syncthreads();
    if (c < 10) {
        float s = fc1b[c];
        for (int k = 0; k < HC; ++k) s = fmaf(sp[k], fc1w[k * 10 + c], s);
        sh[c] = fmaxf(s, 0.f);
    }
    __syncthreads();
    if (c == 0) {
        float o = fc2b[0];
#pragma unroll
        for (int j = 0; j < 10; ++j) o = fmaf(sh[j], fc2w[j], o);
        out[g] = o;
    }
}

extern "C" void kernel_launch(void* const* d_in, const int* in_sizes, int n_in,
                              void* d_out, int out_size, void* d_ws, size_t ws_size,
                              hipStream_t stream) {
    const int N = in_sizes[0] / 64;   // 50000
    const int E = in_sizes[1] / 2;    // 600000
    const int G = out_size;           // 500
    const int CSR_CAP = E + 8 * N + 64;  // pad8 worst case + prefetch margin

    const float* x     = (const float*)d_in[0];
    const int*   ei    = (const int*)d_in[1];
    const int*   batch = (const int*)d_in[2];
    const float* W1 = (const float*)d_in[3];
    const float* as1 = (const float*)d_in[4];
    const float* ad1 = (const float*)d_in[5];
    const float* b1 = (const float*)d_in[6];
    const float* W2 = (const float*)d_in[7];
    const float* as2 = (const float*)d_in[8];
    const float* ad2 = (const float*)d_in[9];
    const float* b2 = (const float*)d_in[10];
    const float* W3 = (const float*)d_in[11];
    const float* as3 = (const float*)d_in[12];
    const float* ad3 = (const float*)d_in[13];
    const float* b3 = (const float*)d_in[14];
    const float* fc1w = (const float*)d_in[15];
    const float* fc1b = (const float*)d_in[16];
    const float* fc2w = (const float*)d_in[17];
    const float* fc2b = (const float*)d_in[18];

    // -------- workspace layout --------
    float* ws = (float*)d_ws;
    float* h    = ws;                            // (N+1)*128
    float* xb0  = h + (size_t)(N + 1) * HC;      // N*128
    float* xb1  = xb0 + (size_t)N * HC;          // N*128
    float* asrc = xb1 + (size_t)N * HC;          // (N+1)*8
    float* adst = asrc + (size_t)(N + 1) * H;    // N*8
    int* ints   = (int*)(adst + (size_t)N * H);
    int* deg8   = ints;                          // 8*N  (becomes base8 cursors)
    int* deg    = deg8 + (size_t)8 * N;          // N
    int* rowptr = deg + N;                       // N+16
    int* gptr   = rowptr + N + 16;               // G+16
    int* partN  = gptr + G + 16;                 // 256
    int* csr    = partN + 256;                   // CSR_CAP

    dim3 blk(256);
    int grid8   = ((E + 7) / 8 + 255) / 256;     // covers E/8 and N/8 threads
    int grid_n  = (N + 255) / 256;
    int grid_agg = (N + 1) / 2;                  // 2 dsts per block (4 waves)
    int nbN = (N + 1023) / 1024;

    // -------- one-time CSR build (graph shared by all 3 layers) --------
    init_kernel<<<(8 * N + 255) / 256, blk, 0, stream>>>(deg8, 8 * N);
    hist8_gptr_kernel<<<grid8, blk, 0, stream>>>(ei, batch, deg8, gptr, E, N, G);
    deg_reduce_kernel<<<grid_n, blk, 0, stream>>>(deg8, deg, N);
    scan_blk_kernel<<<nbN, blk, 0, stream>>>(deg, rowptr, partN, N);
    scan_part_kernel<<<1, blk, 0, stream>>>(partN, rowptr + N, nbN);
    scan_add_kernel<<<nbN, blk, 0, stream>>>(rowptr, partN, N);
    base_fill_kernel<<<grid_n, blk, 0, stream>>>(deg8, rowptr, csr, N);
    scatter8_kernel<<<grid8, blk, 0, stream>>>(ei, deg8, csr, E, N);

    auto run_layer = [&](const float* xin, int K, const float* W, const float* as_,
                         const float* ad_, const float* b, float* out) {
        if (K == 64)
            gemm_att_kernel<64><<<(N + 63) / 64, blk, 0, stream>>>(xin, W, as_, ad_,
                                                                   h, asrc, adst, N);
        else
            gemm_att_kernel<128><<<(N + 63) / 64, blk, 0, stream>>>(xin, W, as_, ad_,
                                                                    h, asrc, adst, N);
        gat_agg_kernel<<<grid_agg, blk, 0, stream>>>(rowptr, csr, h, asrc, adst, b, out, N);
    };

    run_layer(x,   64,  W1, as1, ad1, b1, xb0);
    run_layer(xb0, 128, W2, as2, ad2, b2, xb1);
    run_layer(xb1, 128, W3, as3, ad3, b3, xb0);

    pool_mlp_kernel<<<G, dim3(128), 0, stream>>>(xb0, gptr, fc1w, fc1b, fc2w, fc2b,
                                                 (float*)d_out, G);
}

// Round 12
// 362.117 us; speedup vs baseline: 1.0273x; 1.0251x over previous
//
#include <hip/hip_runtime.h>
#include <hip/hip_bf16.h>

#define H 8
#define C 16
#define HC 128
#define NEG_SLOPE 0.2f

// ---------------- init: zero the 8-way degree counters ----------------
__global__ void init_kernel(int* __restrict__ deg8, int n) {
    int i = blockIdx.x * 256 + threadIdx.x;
    if (i < n) deg8[i] = 0;
}

// ---------------- 8-way histogram (8 edges/thread) + gptr boundaries ----------------
__global__ void hist8_gptr_kernel(const int* __restrict__ ei, const int* __restrict__ batch,
                                  int* __restrict__ deg8, int* __restrict__ gptr,
                                  int E, int N, int G) {
    int t = blockIdx.x * 256 + threadIdx.x;
    int* dg = deg8 + (size_t)(blockIdx.x & 7) * N;
    int e0 = t * 8;
    if (e0 + 7 < E) {
        int4 d4a = *(const int4*)(ei + E + e0);
        int4 d4b = *(const int4*)(ei + E + e0 + 4);
        atomicAdd(&dg[d4a.x], 1);
        atomicAdd(&dg[d4a.y], 1);
        atomicAdd(&dg[d4a.z], 1);
        atomicAdd(&dg[d4a.w], 1);
        atomicAdd(&dg[d4b.x], 1);
        atomicAdd(&dg[d4b.y], 1);
        atomicAdd(&dg[d4b.z], 1);
        atomicAdd(&dg[d4b.w], 1);
    } else if (e0 < E) {
        for (int j = e0; j < E; ++j) atomicAdd(&dg[ei[E + j]], 1);
    }
    int n0 = t * 8;
    if (n0 < N) {
        int prev = (n0 == 0) ? -1 : batch[n0 - 1];
        for (int j = 0; j < 8 && n0 + j < N; ++j) {
            int i = n0 + j;
            int cur = batch[i];
            if (cur != prev)
                for (int g = prev + 1; g <= cur; ++g) gptr[g] = i;
            if (i == N - 1)
                for (int g = cur + 1; g <= G; ++g) gptr[g] = N;
            prev = cur;
        }
    }
}

// ======== scan phase 1: fused deg8-reduce (+1 self loop, pad8) + block scan ========
__global__ void scan_blk_kernel(const int* __restrict__ deg8, int* __restrict__ o,
                                int* __restrict__ p, int n) {
    __shared__ int sh[256];
    int tid = threadIdx.x;
    int base = blockIdx.x * 1024 + tid * 4;
    int4 v = make_int4(1, 1, 1, 1);  // self loop
    if (base + 3 < n) {
#pragma unroll
        for (int c = 0; c < 8; ++c) {
            int4 t4 = *(const int4*)(deg8 + (size_t)c * n + base);
            v.x += t4.x; v.y += t4.y; v.z += t4.z; v.w += t4.w;
        }
    } else {
        v = make_int4(0, 0, 0, 0);
        for (int j = 0; j < 4; ++j) {
            if (base + j < n) {
                int s = 1;
#pragma unroll
                for (int c = 0; c < 8; ++c) s += deg8[(size_t)c * n + base + j];
                (&v.x)[j] = s;
            }
        }
    }
    v.x = (v.x + 7) & ~7; v.y = (v.y + 7) & ~7;
    v.z = (v.z + 7) & ~7; v.w = (v.w + 7) & ~7;
    if (base >= n)     v.x = 0;
    if (base + 1 >= n) v.y = 0;
    if (base + 2 >= n) v.z = 0;
    if (base + 3 >= n) v.w = 0;
    int s = v.x + v.y + v.z + v.w;
    sh[tid] = s;
    __syncthreads();
    for (int off = 1; off < 256; off <<= 1) {
        int t = (tid >= off) ? sh[tid - off] : 0;
        __syncthreads();
        sh[tid] += t;
        __syncthreads();
    }
    int excl = sh[tid] - s;
    int4 ov;
    ov.x = excl; ov.y = ov.x + v.x; ov.z = ov.y + v.y; ov.w = ov.z + v.z;
    if (base + 3 < n) *(int4*)(o + base) = ov;
    else {
        if (base < n)     o[base] = ov.x;
        if (base + 1 < n) o[base + 1] = ov.y;
        if (base + 2 < n) o[base + 2] = ov.z;
        if (base + 3 < n) o[base + 3] = ov.w;
    }
    if (tid == 255) p[blockIdx.x] = sh[255];
}

__global__ void scan_part_kernel(int* __restrict__ p, int* __restrict__ tot, int nb) {
    __shared__ int sh[256];
    int tid = threadIdx.x;
    int v = (tid < nb) ? p[tid] : 0;
    sh[tid] = v;
    __syncthreads();
    for (int off = 1; off < 256; off <<= 1) {
        int t = (tid >= off) ? sh[tid - off] : 0;
        __syncthreads();
        sh[tid] += t;
        __syncthreads();
    }
    if (tid < nb) p[tid] = sh[tid] - v;
    if (tid == 255) *tot = sh[255];
}

__global__ void scan_add_kernel(int* __restrict__ o, const int* __restrict__ p, int n) {
    int off = p[blockIdx.x];
    int base = blockIdx.x * 1024 + threadIdx.x * 4;
    if (base + 3 < n) {
        int4 v = *(const int4*)(o + base);
        v.x += off; v.y += off; v.z += off; v.w += off;
        *(int4*)(o + base) = v;
    } else {
        if (base < n)     o[base] += off;
        if (base + 1 < n) o[base + 1] += off;
        if (base + 2 < n) o[base + 2] += off;
        if (base + 3 < n) o[base + 3] += off;
    }
}

// ---------------- per-copy cursor bases + self-loop + sentinel pads ----------------
__global__ void base_fill_kernel(int* __restrict__ deg8 /* in: counts, out: cursors */,
                                 const int* __restrict__ rowptr, int* __restrict__ csr, int N) {
    int d = blockIdx.x * 256 + threadIdx.x;
    if (d >= N) return;
    int base = rowptr[d];
    csr[base] = d;  // self loop at slot 0
    int run = base + 1;
    int cnt[8];
#pragma unroll
    for (int c = 0; c < 8; ++c) cnt[c] = deg8[(size_t)c * N + d];
#pragma unroll
    for (int c = 0; c < 8; ++c) { deg8[(size_t)c * N + d] = run; run += cnt[c]; }
    int rend = rowptr[d + 1];
    for (int p = run; p < rend; ++p) csr[p] = N;  // sentinel pads
    if (d == 0) {
        int tot = rowptr[N];
        for (int k = 0; k < 64; ++k) csr[tot + k] = N;  // prefetch margin
    }
}

// ---------------- 8-way scatter (8 edges/thread), copy mapping == hist8 ----------------
__global__ void scatter8_kernel(const int* __restrict__ ei, int* __restrict__ base8,
                                int* __restrict__ csr, int E, int N) {
    int t = blockIdx.x * 256 + threadIdx.x;
    int* cur = base8 + (size_t)(blockIdx.x & 7) * N;
    int e0 = t * 8;
    if (e0 + 7 < E) {
        int4 s4a = *(const int4*)(ei + e0);
        int4 s4b = *(const int4*)(ei + e0 + 4);
        int4 d4a = *(const int4*)(ei + E + e0);
        int4 d4b = *(const int4*)(ei + E + e0 + 4);
        int p;
        p = atomicAdd(&cur[d4a.x], 1); csr[p] = s4a.x;
        p = atomicAdd(&cur[d4a.y], 1); csr[p] = s4a.y;
        p = atomicAdd(&cur[d4a.z], 1); csr[p] = s4a.z;
        p = atomicAdd(&cur[d4a.w], 1); csr[p] = s4a.w;
        p = atomicAdd(&cur[d4b.x], 1); csr[p] = s4b.x;
        p = atomicAdd(&cur[d4b.y], 1); csr[p] = s4b.y;
        p = atomicAdd(&cur[d4b.z], 1); csr[p] = s4b.z;
        p = atomicAdd(&cur[d4b.w], 1); csr[p] = s4b.w;
    } else if (e0 < E) {
        for (int j = e0; j < E; ++j) {
            int p = atomicAdd(&cur[ei[E + j]], 1);
            csr[p] = ei[j];
        }
    }
}

// ---------------- fused GEMM + attention coefficients ----------------
// 64x128 tile, 256 threads, each thread 8 rows x 4 cols.
// W staged through LDS in 8-k double-buffered chunks (8x less L2 traffic).
// Block 0 additionally writes the sentinel row (h[n]=0, asrc[n]=-inf).
template <int K>
__global__ void gemm_att_kernel(const float* __restrict__ x, const float* __restrict__ W,
                                const float* __restrict__ as_, const float* __restrict__ ad_,
                                float* __restrict__ h, float* __restrict__ asrc,
                                float* __restrict__ adst, int n) {
    const int ROWS = 64;
    __shared__ float xs[ROWS][HC];      // 32 KB: x tile, then output tile
    __shared__ float wsh[2][8][HC];     // 8 KB: W chunk double-buffer
    int tx = threadIdx.x & 31;
    int ty = threadIdx.x >> 5;
    int row0 = blockIdx.x * ROWS;
    int wrow = threadIdx.x >> 5;        // 0..7
    int wcol = (threadIdx.x & 31) * 4;  // 0..124

    if (blockIdx.x == 0) {
        if (threadIdx.x < HC) h[(size_t)n * HC + threadIdx.x] = 0.f;
        if (threadIdx.x < H)  asrc[(size_t)n * H + threadIdx.x] = -INFINITY;
    }

    const int NV = ROWS * K / 4;
    for (int idx = threadIdx.x; idx < NV; idx += 256) {
        int rr = idx / (K / 4), kk = idx % (K / 4);
        int gr = row0 + rr;
        float4 v = (gr < n) ? ((const float4*)(x + (size_t)gr * K))[kk]
                            : make_float4(0.f, 0.f, 0.f, 0.f);
        *(float4*)(&xs[rr][kk * 4]) = v;
    }
    // preload W chunk 0
    *(float4*)&wsh[0][wrow][wcol] = *(const float4*)(W + (size_t)wrow * HC + wcol);
    __syncthreads();

    float acc[8][4];
#pragma unroll
    for (int r = 0; r < 8; ++r)
#pragma unroll
        for (int c = 0; c < 4; ++c) acc[r][c] = 0.f;

    const int NCH = K / 8;
    for (int c = 0; c < NCH; ++c) {
        int cur = c & 1;
        if (c + 1 < NCH)
            *(float4*)&wsh[cur ^ 1][wrow][wcol] =
                *(const float4*)(W + (size_t)((c + 1) * 8 + wrow) * HC + wcol);
#pragma unroll
        for (int k2 = 0; k2 < 2; ++k2) {
            float4 wv[4];
#pragma unroll
            for (int kk = 0; kk < 4; ++kk)
                wv[kk] = *(const float4*)&wsh[cur][k2 * 4 + kk][tx * 4];
            int kx = c * 8 + k2 * 4;
#pragma unroll
            for (int r = 0; r < 8; ++r) {
                float4 xr = *(const float4*)(&xs[ty * 8 + r][kx]);
                acc[r][0] = fmaf(xr.x, wv[0].x, acc[r][0]);
                acc[r][1] = fmaf(xr.x, wv[0].y, acc[r][1]);
                acc[r][2] = fmaf(xr.x, wv[0].z, acc[r][2]);
                acc[r][3] = fmaf(xr.x, wv[0].w, acc[r][3]);
                acc[r][0] = fmaf(xr.y, wv[1].x, acc[r][0]);
                acc[r][1] = fmaf(xr.y, wv[1].y, acc[r][1]);
                acc[r][2] = fmaf(xr.y, wv[1].z, acc[r][2]);
                acc[r][3] = fmaf(xr.y, wv[1].w, acc[r][3]);
                acc[r][0] = fmaf(xr.z, wv[2].x, acc[r][0]);
                acc[r][1] = fmaf(xr.z, wv[2].y, acc[r][1]);
                acc[r][2] = fmaf(xr.z, wv[2].z, acc[r][2]);
                acc[r][3] = fmaf(xr.z, wv[2].w, acc[r][3]);
                acc[r][0] = fmaf(xr.w, wv[3].x, acc[r][0]);
                acc[r][1] = fmaf(xr.w, wv[3].y, acc[r][1]);
                acc[r][2] = fmaf(xr.w, wv[3].z, acc[r][2]);
                acc[r][3] = fmaf(xr.w, wv[3].w, acc[r][3]);
            }
        }
        __syncthreads();
    }
#pragma unroll
    for (int r = 0; r < 8; ++r) {
        float4 o = make_float4(acc[r][0], acc[r][1], acc[r][2], acc[r][3]);
        *(float4*)(&xs[ty * 8 + r][tx * 4]) = o;
        int row = row0 + ty * 8 + r;
        if (row < n) *(float4*)(h + (size_t)row * HC + tx * 4) = o;
    }
    __syncthreads();

    // attention dots: 512 (row,head) pairs, 2 per thread
#pragma unroll
    for (int rep = 0; rep < 2; ++rep) {
        int pidx = threadIdx.x + rep * 256;
        int row = pidx >> 3;
        int hd = pidx & 7;
        if (row0 + row < n) {
            const float4* hv = (const float4*)&xs[row][hd * 16];
            const float4* sv = (const float4*)(as_ + hd * 16);
            const float4* dv = (const float4*)(ad_ + hd * 16);
            float s = 0.f, d = 0.f;
#pragma unroll
            for (int j = 0; j < 4; ++j) {
                float4 a = hv[j], u = sv[j], v = dv[j];
                s += a.x * u.x + a.y * u.y + a.z * u.z + a.w * u.w;
                d += a.x * v.x + a.y * v.y + a.z * v.z + a.w * v.w;
            }
            asrc[(size_t)(row0 + row) * H + hd] = s;
            adst[(size_t)(row0 + row) * H + hd] = d;
        }
    }
}

// ---------------- fused GAT aggregation: one wave per destination ----------------
// No-max softmax; pad8 sentinel rows; 8-deep 3-stage pipeline (R9 structure).
__global__ void gat_agg_kernel(const int* __restrict__ rowptr, const int* __restrict__ csr_src,
                               const float* __restrict__ h, const float* __restrict__ asrc,
                               const float* __restrict__ adst, const float* __restrict__ bias,
                               float* __restrict__ out, int N) {
    int dst = (blockIdx.x * 256 + threadIdx.x) >> 6;  // one wave per dst
    if (dst >= N) return;
    int lane = threadIdx.x & 63;
    int hd = lane >> 3;
    int beg = rowptr[dst], end = rowptr[dst + 1];
    float ad = adst[(size_t)dst * H + hd];
    const float2* h2 = (const float2*)h;  // row stride = 64 float2

    float z = 0.f, a0 = 0.f, a1 = 0.f;
    int i0, i1, i2, i3, i4, i5, i6, i7;
    float e0, e1, e2, e3, e4, e5, e6, e7;
    float2 v0, v1, v2, v3, v4, v5, v6, v7;

#define LOADI(S, J) i##S = csr_src[(J)];
#define LOADV(S)                                                           \
    { e##S = asrc[(size_t)i##S * H + hd]; v##S = h2[(size_t)i##S * 64 + lane]; }
#define PROCE(S)                                                           \
    {   float e = e##S + ad;                                               \
        e = e > 0.f ? e : NEG_SLOPE * e;                                   \
        float w = __expf(e);                                               \
        z += w;                                                            \
        a0 = fmaf(w, v##S.x, a0);                                          \
        a1 = fmaf(w, v##S.y, a1);                                          \
    }
    LOADI(0, beg)     LOADI(1, beg + 1) LOADI(2, beg + 2) LOADI(3, beg + 3)
    LOADI(4, beg + 4) LOADI(5, beg + 5) LOADI(6, beg + 6) LOADI(7, beg + 7)
    LOADV(0) LOADV(1) LOADV(2) LOADV(3) LOADV(4) LOADV(5) LOADV(6) LOADV(7)
    LOADI(0, beg + 8)  LOADI(1, beg + 9)  LOADI(2, beg + 10) LOADI(3, beg + 11)
    LOADI(4, beg + 12) LOADI(5, beg + 13) LOADI(6, beg + 14) LOADI(7, beg + 15)

    for (int j = beg; j < end; j += 8) {
        PROCE(0) LOADV(0)
        PROCE(1) LOADV(1)
        PROCE(2) LOADV(2)
        PROCE(3) LOADV(3)
        PROCE(4) LOADV(4)
        PROCE(5) LOADV(5)
        PROCE(6) LOADV(6)
        PROCE(7) LOADV(7)
        LOADI(0, j + 16) LOADI(1, j + 17) LOADI(2, j + 18) LOADI(3, j + 19)
        LOADI(4, j + 20) LOADI(5, j + 21) LOADI(6, j + 22) LOADI(7, j + 23)
    }
#undef LOADI
#undef LOADV
#undef PROCE
    float inv = 1.f / (z + 1e-16f);
    int c2 = lane * 2;
    float r0 = fmaxf(a0 * inv + bias[c2], 0.f);
    float r1 = fmaxf(a1 * inv + bias[c2 + 1], 0.f);
    *(float2*)(out + (size_t)dst * HC + c2) = make_float2(r0, r1);
}

// ---------------- fused global mean pool + MLP: one block (128 threads) per graph ---
__global__ void pool_mlp_kernel(const float* __restrict__ x, const int* __restrict__ gptr,
                                const float* __restrict__ fc1w, const float* __restrict__ fc1b,
                                const float* __restrict__ fc2w, const float* __restrict__ fc2b,
                                float* __restrict__ out, int G) {
    __shared__ float sp[HC];
    __shared__ float sh[10];
    int g = blockIdx.x;
    int c = threadIdx.x;  // 0..127
    int beg = gptr[g], end = gptr[g + 1];
    float acc = 0.f;
    for (int n = beg; n < end; ++n) acc += x[(size_t)n * HC + c];
    sp[c] = acc / fmaxf((float)(end - beg), 1.f);
    __syncthreads();
    if (c < 10) {
        float s = fc1b[c];
        for (int k = 0; k < HC; ++k) s = fmaf(sp[k], fc1w[k * 10 + c], s);
        sh[c] = fmaxf(s, 0.f);
    }
    __syncthreads();
    if (c == 0) {
        float o = fc2b[0];
#pragma unroll
        for (int j = 0; j < 10; ++j) o = fmaf(sh[j], fc2w[j], o);
        out[g] = o;
    }
}

extern "C" void kernel_launch(void* const* d_in, const int* in_sizes, int n_in,
                              void* d_out, int out_size, void* d_ws, size_t ws_size,
                              hipStream_t stream) {
    const int N = in_sizes[0] / 64;   // 50000
    const int E = in_sizes[1] / 2;    // 600000
    const int G = out_size;           // 500
    const int CSR_CAP = E + 8 * N + 64;  // pad8 worst case + prefetch margin

    const float* x     = (const float*)d_in[0];
    const int*   ei    = (const int*)d_in[1];
    const int*   batch = (const int*)d_in[2];
    const float* W1 = (const float*)d_in[3];
    const float* as1 = (const float*)d_in[4];
    const float* ad1 = (const float*)d_in[5];
    const float* b1 = (const float*)d_in[6];
    const float* W2 = (const float*)d_in[7];
    const float* as2 = (const float*)d_in[8];
    const float* ad2 = (const float*)d_in[9];
    const float* b2 = (const float*)d_in[10];
    const float* W3 = (const float*)d_in[11];
    const float* as3 = (const float*)d_in[12];
    const float* ad3 = (const float*)d_in[13];
    const float* b3 = (const float*)d_in[14];
    const float* fc1w = (const float*)d_in[15];
    const float* fc1b = (const float*)d_in[16];
    const float* fc2w = (const float*)d_in[17];
    const float* fc2b = (const float*)d_in[18];

    // -------- workspace layout --------
    float* ws = (float*)d_ws;
    float* h    = ws;                            // (N+1)*128
    float* xb0  = h + (size_t)(N + 1) * HC;      // N*128
    float* xb1  = xb0 + (size_t)N * HC;          // N*128
    float* asrc = xb1 + (size_t)N * HC;          // (N+1)*8
    float* adst = asrc + (size_t)(N + 1) * H;    // N*8
    int* ints   = (int*)(adst + (size_t)N * H);
    int* deg8   = ints;                          // 8*N  (becomes base8 cursors)
    int* rowptr = deg8 + (size_t)8 * N;          // N+16
    int* gptr   = rowptr + N + 16;               // G+16
    int* partN  = gptr + G + 16;                 // 256
    int* csr    = partN + 256;                   // CSR_CAP

    dim3 blk(256);
    int grid8   = ((E + 7) / 8 + 255) / 256;     // covers E/8 and N/8 threads
    int grid_n  = (N + 255) / 256;
    int grid_agg = (N * 64 + 255) / 256;
    int nbN = (N + 1023) / 1024;

    // -------- one-time CSR build (graph shared by all 3 layers) --------
    init_kernel<<<(8 * N + 255) / 256, blk, 0, stream>>>(deg8, 8 * N);
    hist8_gptr_kernel<<<grid8, blk, 0, stream>>>(ei, batch, deg8, gptr, E, N, G);
    scan_blk_kernel<<<nbN, blk, 0, stream>>>(deg8, rowptr, partN, N);
    scan_part_kernel<<<1, blk, 0, stream>>>(partN, rowptr + N, nbN);
    scan_add_kernel<<<nbN, blk, 0, stream>>>(rowptr, partN, N);
    base_fill_kernel<<<grid_n, blk, 0, stream>>>(deg8, rowptr, csr, N);
    scatter8_kernel<<<grid8, blk, 0, stream>>>(ei, deg8, csr, E, N);

    auto run_layer = [&](const float* xin, int K, const float* W, const float* as_,
                         const float* ad_, const float* b, float* out) {
        if (K == 64)
            gemm_att_kernel<64><<<(N + 63) / 64, blk, 0, stream>>>(xin, W, as_, ad_,
                                                                   h, asrc, adst, N);
        else
            gemm_att_kernel<128><<<(N + 63) / 64, blk, 0, stream>>>(xin, W, as_, ad_,
                                                                    h, asrc, adst, N);
        gat_agg_kernel<<<grid_agg, blk, 0, stream>>>(rowptr, csr, h, asrc, adst, b, out, N);
    };

    run_layer(x,   64,  W1, as1, ad1, b1, xb0);
    run_layer(xb0, 128, W2, as2, ad2, b2, xb1);
    run_layer(xb1, 128, W3, as3, ad3, b3, xb0);

    pool_mlp_kernel<<<G, dim3(128), 0, stream>>>(xb0, gptr, fc1w, fc1b, fc2w, fc2b,
                                                 (float*)d_out, G);
}